// Round 1
// baseline (9775.729 us; speedup 1.0000x reference)
//
#include <hip/hip_runtime.h>
#include <math.h>

// Problem constants
#define BB   64
#define TT   256
#define VV   65
#define DD   384
#define HH   6
#define HDD  64
#define LL   6
#define FFD  1536
#define BT   (BB * TT)        // 16384 rows
#define EPSL 1e-5f
#define SCALE 0.05103103630798287f  // 384^-0.5

// ---------------------------------------------------------------------------
// Embedding: x[b,t,:] = tok_emb[idx[b,t],:] + pos_emb[t,:]   (float4 vectorized)
// ---------------------------------------------------------------------------
__global__ __launch_bounds__(256) void embed_k(const int* __restrict__ idx,
                                               const float* __restrict__ tok,
                                               const float* __restrict__ pos,
                                               float* __restrict__ x) {
    int i = blockIdx.x * 256 + threadIdx.x;     // float4 index, total BT*96
    int bt = i / 96;
    int d4 = i - bt * 96;
    int t  = bt & (TT - 1);
    float4 a = ((const float4*)tok)[(size_t)idx[bt] * 96 + d4];
    float4 p = ((const float4*)pos)[(size_t)t * 96 + d4];
    float4 o;
    o.x = a.x + p.x; o.y = a.y + p.y; o.z = a.z + p.z; o.w = a.w + p.w;
    ((float4*)x)[i] = o;
}

// ---------------------------------------------------------------------------
// LayerNorm: one wave (64 lanes) per row of 384; block = 4 rows
// ---------------------------------------------------------------------------
__global__ __launch_bounds__(256) void ln_k(const float* __restrict__ in,
                                            const float* __restrict__ w,
                                            const float* __restrict__ b,
                                            float* __restrict__ out) {
    int row  = blockIdx.x * 4 + (threadIdx.x >> 6);
    int lane = threadIdx.x & 63;
    const float* p = in + (size_t)row * DD;
    float vals[6];
    float s = 0.f;
#pragma unroll
    for (int j = 0; j < 6; ++j) { vals[j] = p[lane + 64 * j]; s += vals[j]; }
#pragma unroll
    for (int off = 32; off; off >>= 1) s += __shfl_xor(s, off);
    float mean = s * (1.0f / DD);
    float s2 = 0.f;
#pragma unroll
    for (int j = 0; j < 6; ++j) { float d = vals[j] - mean; s2 += d * d; }
#pragma unroll
    for (int off = 32; off; off >>= 1) s2 += __shfl_xor(s2, off);
    float rstd = rsqrtf(s2 * (1.0f / DD) + EPSL);
    float* po = out + (size_t)row * DD;
#pragma unroll
    for (int j = 0; j < 6; ++j) {
        int c = lane + 64 * j;
        po[c] = (vals[j] - mean) * rstd * w[c] + b[c];
    }
}

// ---------------------------------------------------------------------------
// fp32 tiled GEMM: C[M,N] = A[M,K] @ B[K,N] (+bias) (+residual) (ReLU)
// BLAYOUT 0: B row-major [K,N].  BLAYOUT 1: qkv weights [H][K][64], n = h*64+e.
// BM=BN=64, BK=16, 256 threads, 4x4 per thread.
// M, K are multiples of 64/16; N may be ragged (head GEMM N=65).
// ---------------------------------------------------------------------------
template <int BLAYOUT>
__global__ __launch_bounds__(256) void gemm_k(const float* __restrict__ A,
                                              const float* __restrict__ B,
                                              const float* __restrict__ bias,
                                              const float* __restrict__ res,
                                              float* __restrict__ C,
                                              int M, int N, int K, int relu) {
    __shared__ float As[16][65];
    __shared__ float Bs[16][65];
    const int t  = threadIdx.x;
    const int m0 = blockIdx.y * 64;
    const int n0 = blockIdx.x * 64;
    const int tm = t >> 4, tn = t & 15;
    const int am = t >> 2, ak4 = (t & 3) * 4;   // A tile load coords
    const int bk = t >> 4, bn4 = (t & 15) * 4;  // B tile load coords

    float acc[4][4] = {{0.f}};

    for (int k0 = 0; k0 < K; k0 += 16) {
        // stage loads into registers (previous tile still being consumed)
        const float4 av = *(const float4*)(A + (size_t)(m0 + am) * K + k0 + ak4);
        float bv[4];
        if (BLAYOUT == 1) {
            const float4 b4 = *(const float4*)(B + ((size_t)(n0 >> 6) * K + (k0 + bk)) * 64 + bn4);
            bv[0] = b4.x; bv[1] = b4.y; bv[2] = b4.z; bv[3] = b4.w;
        } else {
            if (n0 + bn4 + 3 < N) {
                const float4 b4 = *(const float4*)(B + (size_t)(k0 + bk) * N + n0 + bn4);
                bv[0] = b4.x; bv[1] = b4.y; bv[2] = b4.z; bv[3] = b4.w;
            } else {
#pragma unroll
                for (int j = 0; j < 4; ++j) {
                    int col = n0 + bn4 + j;
                    bv[j] = (col < N) ? B[(size_t)(k0 + bk) * N + col] : 0.f;
                }
            }
        }
        __syncthreads();
        As[ak4 + 0][am] = av.x;
        As[ak4 + 1][am] = av.y;
        As[ak4 + 2][am] = av.z;
        As[ak4 + 3][am] = av.w;
#pragma unroll
        for (int j = 0; j < 4; ++j) Bs[bk][bn4 + j] = bv[j];
        __syncthreads();
#pragma unroll
        for (int kk = 0; kk < 16; ++kk) {
            float a0 = As[kk][tm * 4 + 0];
            float a1 = As[kk][tm * 4 + 1];
            float a2 = As[kk][tm * 4 + 2];
            float a3 = As[kk][tm * 4 + 3];
            float b0 = Bs[kk][tn * 4 + 0];
            float b1 = Bs[kk][tn * 4 + 1];
            float b2 = Bs[kk][tn * 4 + 2];
            float b3 = Bs[kk][tn * 4 + 3];
            acc[0][0] += a0 * b0; acc[0][1] += a0 * b1; acc[0][2] += a0 * b2; acc[0][3] += a0 * b3;
            acc[1][0] += a1 * b0; acc[1][1] += a1 * b1; acc[1][2] += a1 * b2; acc[1][3] += a1 * b3;
            acc[2][0] += a2 * b0; acc[2][1] += a2 * b1; acc[2][2] += a2 * b2; acc[2][3] += a2 * b3;
            acc[3][0] += a3 * b0; acc[3][1] += a3 * b1; acc[3][2] += a3 * b2; acc[3][3] += a3 * b3;
        }
    }

#pragma unroll
    for (int i = 0; i < 4; ++i) {
        int row = m0 + tm * 4 + i;
#pragma unroll
        for (int j = 0; j < 4; ++j) {
            int col = n0 + tn * 4 + j;
            if (col < N) {
                float v = acc[i][j];
                if (bias) v += bias[col];
                if (res)  v += res[(size_t)row * N + col];
                if (relu) v = fmaxf(v, 0.f);
                C[(size_t)row * N + col] = v;
            }
        }
    }
}

// ---------------------------------------------------------------------------
// Attention: one block per (qtile of 64 rows, head, batch). T=256, HD=64.
// Q,K,V are [BT, 384] with head offset h*64. O written likewise (concat heads).
// LDS: Ks[256][65] (reused for V), Qs[64][65], S[64][257]  ~149 KB.
// ---------------------------------------------------------------------------
__global__ __launch_bounds__(256) void attn_k(const float* __restrict__ Q,
                                              const float* __restrict__ K,
                                              const float* __restrict__ V,
                                              float* __restrict__ O) {
    __shared__ float Ks[256][65];   // K rows; later aliased with V rows
    __shared__ float Qs[64][65];
    __shared__ float S[64][257];

    const int qt = blockIdx.x;            // 0..3
    const int hh = blockIdx.y;            // 0..5
    const int bb = blockIdx.z;            // 0..63
    const int t  = threadIdx.x;           // 0..255
    const int q0 = qt * 64;
    const size_t baseBH = ((size_t)bb * TT) * DD + (size_t)hh * HDD;

    const int e  = t & 63;
    const int s0 = t >> 6;

    // load K tile: 256 rows x 64
    for (int it = 0; it < 64; ++it) {
        int s = s0 + 4 * it;
        Ks[s][e] = K[baseBH + (size_t)s * DD + e];
    }
    // load Q tile: 64 rows
    for (int it = 0; it < 16; ++it) {
        int r = s0 + 4 * it;
        Qs[r][e] = Q[baseBH + (size_t)(q0 + r) * DD + e];
    }
    __syncthreads();

    // S = Q K^T * scale, causal mask.  Thread owns column c = t.
    {
        const int c = t;
        for (int r = 0; r < 64; ++r) {
            int grow = q0 + r;
            float acc;
            if (c <= grow) {
                acc = 0.f;
#pragma unroll
                for (int ee = 0; ee < 64; ++ee) acc += Qs[r][ee] * Ks[c][ee];
                acc *= SCALE;
            } else {
                acc = -1e30f;
            }
            S[r][c] = acc;
        }
    }
    __syncthreads();

    // load V into Ks (K no longer needed)
    for (int it = 0; it < 64; ++it) {
        int s = s0 + 4 * it;
        Ks[s][e] = V[baseBH + (size_t)s * DD + e];
    }

    // softmax: wave w -> rows w*16 .. w*16+15; 4 lanes per row, interleaved cols
    {
        const int w    = t >> 6;
        const int lane = t & 63;
        const int r    = w * 16 + (lane & 15);
        const int c4   = lane >> 4;
        float vals[64];
        float mx = -1e30f;
#pragma unroll
        for (int jj = 0; jj < 64; ++jj) {
            float sv = S[r][c4 + 4 * jj];
            vals[jj] = sv;
            mx = fmaxf(mx, sv);
        }
        mx = fmaxf(mx, __shfl_xor(mx, 16));
        mx = fmaxf(mx, __shfl_xor(mx, 32));
        float sum = 0.f;
#pragma unroll
        for (int jj = 0; jj < 64; ++jj) {
            float p = __expf(vals[jj] - mx);
            vals[jj] = p;
            sum += p;
        }
        sum += __shfl_xor(sum, 16);
        sum += __shfl_xor(sum, 32);
        float inv = 1.0f / sum;
#pragma unroll
        for (int jj = 0; jj < 64; ++jj) S[r][c4 + 4 * jj] = vals[jj] * inv;
    }
    __syncthreads();

    // O = P @ V.  Thread owns (row rr, 16 output cols).
    {
        const int rr = t >> 2;
        const int e0 = (t & 3) * 16;
        const int jmax = q0 + rr;            // causal: P[rr][j]=0 beyond
        float acc[16] = {0.f};
        for (int j = 0; j <= jmax; ++j) {
            float p = S[rr][j];
#pragma unroll
            for (int ee = 0; ee < 16; ++ee) acc[ee] += p * Ks[j][e0 + ee];
        }
        float* po = O + baseBH + (size_t)(q0 + rr) * DD + e0;
#pragma unroll
        for (int ee = 0; ee < 16; ++ee) po[ee] = acc[ee];
    }
}

// ---------------------------------------------------------------------------
// Host orchestration
// ---------------------------------------------------------------------------
extern "C" void kernel_launch(void* const* d_in, const int* in_sizes, int n_in,
                              void* d_out, int out_size, void* d_ws, size_t ws_size,
                              hipStream_t stream) {
    const int*   idx     = (const int*)d_in[0];
    const float* tok_emb = (const float*)d_in[1];
    const float* pos_emb = (const float*)d_in[2];
    const float* ln1_w   = (const float*)d_in[3];
    const float* ln1_b   = (const float*)d_in[4];
    const float* wq      = (const float*)d_in[5];
    const float* wk      = (const float*)d_in[6];
    const float* wv      = (const float*)d_in[7];
    const float* proj_w  = (const float*)d_in[8];
    const float* proj_b  = (const float*)d_in[9];
    const float* ln2_w   = (const float*)d_in[10];
    const float* ln2_b   = (const float*)d_in[11];
    const float* ff_w1   = (const float*)d_in[12];
    const float* ff_b1   = (const float*)d_in[13];
    const float* ff_w2   = (const float*)d_in[14];
    const float* ff_b2   = (const float*)d_in[15];
    const float* lnf_w   = (const float*)d_in[16];
    const float* lnf_b   = (const float*)d_in[17];
    const float* head_w  = (const float*)d_in[18];
    const float* head_b  = (const float*)d_in[19];
    float* out = (float*)d_out;

    const size_t actN = (size_t)BT * DD;        // 6291456 floats
    float* x  = (float*)d_ws;
    float* h  = x + actN;
    float* q  = h + actN;
    float* k  = q + actN;
    float* v  = k + actN;
    float* ff = v + actN;                       // BT * FFD floats

    const dim3 blk(256);

    // embedding
    embed_k<<<dim3((BT * 96) / 256), blk, 0, stream>>>(idx, tok_emb, pos_emb, x);

    const dim3 gLN(BT / 4);
    const dim3 gAttn(4, HH, BB);
    const dim3 gD(DD / 64, BT / 64);            // N=384 GEMMs
    const dim3 gFF(FFD / 64, BT / 64);          // N=1536
    const dim3 gHead((VV + 63) / 64, BT / 64);  // N=65

    for (int l = 0; l < LL; ++l) {
        const size_t wOff  = (size_t)l * HH * DD * HDD;   // qkv weights per layer
        const size_t dOff  = (size_t)l * DD;
        const size_t pOff  = (size_t)l * DD * DD;
        const size_t f1Off = (size_t)l * DD * FFD;
        const size_t f2Off = (size_t)l * FFD * DD;

        ln_k<<<gLN, blk, 0, stream>>>(x, ln1_w + dOff, ln1_b + dOff, h);

        gemm_k<1><<<gD, blk, 0, stream>>>(h, wq + wOff, nullptr, nullptr, q, BT, DD, DD, 0);
        gemm_k<1><<<gD, blk, 0, stream>>>(h, wk + wOff, nullptr, nullptr, k, BT, DD, DD, 0);
        gemm_k<1><<<gD, blk, 0, stream>>>(h, wv + wOff, nullptr, nullptr, v, BT, DD, DD, 0);

        attn_k<<<gAttn, blk, 0, stream>>>(q, k, v, h);   // h <- concat heads

        // x = x + h @ proj_w + proj_b
        gemm_k<0><<<gD, blk, 0, stream>>>(h, proj_w + pOff, proj_b + dOff, x, x, BT, DD, DD, 0);

        ln_k<<<gLN, blk, 0, stream>>>(x, ln2_w + dOff, ln2_b + dOff, h);

        // ff = relu(h @ ff_w1 + b1)
        gemm_k<0><<<gFF, blk, 0, stream>>>(h, ff_w1 + f1Off, ff_b1 + (size_t)l * FFD, nullptr, ff,
                                           BT, FFD, DD, 1);
        // x = x + ff @ ff_w2 + b2
        gemm_k<0><<<gD, blk, 0, stream>>>(ff, ff_w2 + f2Off, ff_b2 + dOff, x, x, BT, DD, FFD, 0);
    }

    ln_k<<<gLN, blk, 0, stream>>>(x, lnf_w, lnf_b, h);
    gemm_k<0><<<gHead, blk, 0, stream>>>(h, head_w, head_b, nullptr, out, BT, VV, DD, 0);
}

// Round 2
// 2979.747 us; speedup vs baseline: 3.2807x; 3.2807x over previous
//
#include <hip/hip_runtime.h>
#include <hip/hip_bf16.h>
#include <math.h>

// Problem constants
#define BB   64
#define TT   256
#define VV   65
#define DD   384
#define HH   6
#define HDD  64
#define LL   6
#define FFD  1536
#define BT   (BB * TT)        // 16384 rows
#define EPSL 1e-5f
#define SCALE 0.05103103630798287f  // 384^-0.5

using bf16x8 = __attribute__((ext_vector_type(8))) short;
using f32x4  = __attribute__((ext_vector_type(4))) float;

__device__ __forceinline__ short f2bf(float f) {
    __hip_bfloat16 h = __float2bfloat16(f);
    return *reinterpret_cast<short*>(&h);
}

__device__ __forceinline__ void load_lds16(const void* g, void* lds_base) {
    // dest = wave-uniform LDS base; HW scatters lane i at base + i*16
    __builtin_amdgcn_global_load_lds(
        (const __attribute__((address_space(1))) void*)g,
        (__attribute__((address_space(3))) void*)lds_base,
        16, 0, 0);
}

// ---------------------------------------------------------------------------
// Embedding: x[b,t,:] = tok_emb[idx[b,t],:] + pos_emb[t,:]
// ---------------------------------------------------------------------------
__global__ __launch_bounds__(256) void embed_k(const int* __restrict__ idx,
                                               const float* __restrict__ tok,
                                               const float* __restrict__ pos,
                                               float* __restrict__ x) {
    int i = blockIdx.x * 256 + threadIdx.x;     // float4 index, total BT*96
    int bt = i / 96;
    int d4 = i - bt * 96;
    int t  = bt & (TT - 1);
    float4 a = ((const float4*)tok)[(size_t)idx[bt] * 96 + d4];
    float4 p = ((const float4*)pos)[(size_t)t * 96 + d4];
    float4 o;
    o.x = a.x + p.x; o.y = a.y + p.y; o.z = a.z + p.z; o.w = a.w + p.w;
    ((float4*)x)[i] = o;
}

// ---------------------------------------------------------------------------
// LayerNorm fp32 in -> bf16 out. One wave per row of 384; block = 4 rows.
// ---------------------------------------------------------------------------
__global__ __launch_bounds__(256) void ln_k(const float* __restrict__ in,
                                            const float* __restrict__ w,
                                            const float* __restrict__ b,
                                            short* __restrict__ out) {
    int row  = blockIdx.x * 4 + (threadIdx.x >> 6);
    int lane = threadIdx.x & 63;
    const float* p = in + (size_t)row * DD;
    float vals[6];
    float s = 0.f;
#pragma unroll
    for (int j = 0; j < 6; ++j) { vals[j] = p[lane + 64 * j]; s += vals[j]; }
#pragma unroll
    for (int off = 32; off; off >>= 1) s += __shfl_xor(s, off);
    float mean = s * (1.0f / DD);
    float s2 = 0.f;
#pragma unroll
    for (int j = 0; j < 6; ++j) { float d = vals[j] - mean; s2 += d * d; }
#pragma unroll
    for (int off = 32; off; off >>= 1) s2 += __shfl_xor(s2, off);
    float rstd = rsqrtf(s2 * (1.0f / DD) + EPSL);
    short* po = out + (size_t)row * DD;
#pragma unroll
    for (int j = 0; j < 6; ++j) {
        int c = lane + 64 * j;
        po[c] = f2bf((vals[j] - mean) * rstd * w[c] + b[c]);
    }
}

// ---------------------------------------------------------------------------
// Weight transpose+convert: W[K][N] f32 -> Wt[Npad][K] bf16 (zero rows >= N).
// Tile 32x32 via LDS. grid: (Npad/32, K/32, layers)
// ---------------------------------------------------------------------------
__global__ __launch_bounds__(256) void wconv_k(const float* __restrict__ W,
                                               short* __restrict__ Wt,
                                               int K, int N, int Npad) {
    __shared__ float tile[32][33];
    W  += (size_t)blockIdx.z * K * N;
    Wt += (size_t)blockIdx.z * Npad * K;
    const int t  = threadIdx.x;
    const int c  = t & 31;
    const int r8 = t >> 5;              // 0..7
    const int k0 = blockIdx.y * 32;
    const int n0 = blockIdx.x * 32;
#pragma unroll
    for (int p = 0; p < 4; ++p) {
        int kk = r8 + 8 * p;
        int n  = n0 + c;
        tile[kk][c] = (n < N) ? W[(size_t)(k0 + kk) * N + n] : 0.f;
    }
    __syncthreads();
#pragma unroll
    for (int p = 0; p < 4; ++p) {
        int nl = r8 + 8 * p;
        Wt[(size_t)(n0 + nl) * K + k0 + c] = f2bf(tile[c][nl]);
    }
}

// ---------------------------------------------------------------------------
// QKV weight convert: wq/wk/wv [L][H][D][HD] f32 -> WqkvT [L][1152][384] bf16
// row n: 0..383 q (h*64+e), 384..767 k, 768..1151 v;  Wt[n][kdim] = w[h][kdim][e]
// ---------------------------------------------------------------------------
__global__ __launch_bounds__(256) void qkvconv_k(const float* __restrict__ wq,
                                                 const float* __restrict__ wk,
                                                 const float* __restrict__ wv,
                                                 short* __restrict__ Wt) {
    int tid = blockIdx.x * 256 + threadIdx.x;   // total L*3*H*384*64 = 2654208
    int e  = tid & 63;
    int k  = (tid >> 6) % 384;
    int r2 = (tid >> 6) / 384;
    int h  = r2 % 6;
    int r3 = r2 / 6;
    int part = r3 % 3;
    int l  = r3 / 3;
    const float* src = (part == 0) ? wq : (part == 1) ? wk : wv;
    float v = src[(((size_t)l * 6 + h) * 384 + k) * 64 + e];
    Wt[((size_t)l * 1152 + part * 384 + h * 64 + e) * 384 + k] = f2bf(v);
}

// ---------------------------------------------------------------------------
// bf16 MFMA GEMM: C[M,N] = A[M,K] @ Bt[N,K]^T  (+bias)(+res)(ReLU)
// A bf16 row-major stride K; Bt bf16 [Npad][K].
// Tile 128x128, BK=64, 4 waves (2x2), wave tile 64x64 = 4x4 frags 16x16x32.
// LDS linear + XOR chunk swizzle (chunk ^= row&7), pre-swizzled global src.
// ---------------------------------------------------------------------------
__global__ __launch_bounds__(256) void gemm_bf16_k(
    const short* __restrict__ A,
    const short* __restrict__ Bt,
    const float* __restrict__ bias,
    const float* __restrict__ res,
    float* __restrict__ out32,
    short* __restrict__ out16,
    int M, int K, int ldC, int ld16, int Nmax, int relu) {
    __shared__ short As[128 * 64];
    __shared__ short Bs[128 * 64];
    const int t  = threadIdx.x;
    const int w  = t >> 6;
    const int l  = t & 63;
    const int m0 = blockIdx.y * 128;
    const int n0 = blockIdx.x * 128;
    const int wr = w >> 1, wc = w & 1;
    const int fr = l & 15, fq = l >> 4;

    // staging geometry: slot S=(w*4+qi)*1024 + l*16 ; r=S>>7 ; c=(S>>4)&7 ; c'=c^(r&7)
    int srow[4], scol[4];
#pragma unroll
    for (int qi = 0; qi < 4; ++qi) {
        int S = (w * 4 + qi) * 1024 + l * 16;
        int r = S >> 7;
        int c = (S >> 4) & 7;
        srow[qi] = r;
        scol[qi] = c ^ (r & 7);
    }

    f32x4 acc[4][4];
#pragma unroll
    for (int i = 0; i < 4; ++i)
#pragma unroll
        for (int j = 0; j < 4; ++j) acc[i][j] = (f32x4)(0.0f);

    for (int k0 = 0; k0 < K; k0 += 64) {
        __syncthreads();   // previous tile fully consumed
#pragma unroll
        for (int qi = 0; qi < 4; ++qi) {
            const short* ga = A + (size_t)(m0 + srow[qi]) * K + k0 + scol[qi] * 8;
            load_lds16(ga, (char*)As + (w * 4 + qi) * 1024);
        }
#pragma unroll
        for (int qi = 0; qi < 4; ++qi) {
            const short* gb = Bt + (size_t)(n0 + srow[qi]) * K + k0 + scol[qi] * 8;
            load_lds16(gb, (char*)Bs + (w * 4 + qi) * 1024);
        }
        asm volatile("s_waitcnt vmcnt(0)" ::: "memory");
        __syncthreads();   // all waves' tiles landed

#pragma unroll
        for (int kk = 0; kk < 64; kk += 32) {
            bf16x8 af[4], bfv[4];
            const int kc = kk >> 3;   // chunk base 0 or 4
#pragma unroll
            for (int mf = 0; mf < 4; ++mf) {
                int ar = wr * 64 + mf * 16 + fr;
                int byte = ar * 128 + (((kc + fq) ^ (ar & 7)) << 4);
                af[mf] = *reinterpret_cast<const bf16x8*>((const char*)As + byte);
            }
#pragma unroll
            for (int nf = 0; nf < 4; ++nf) {
                int br = wc * 64 + nf * 16 + fr;
                int byte = br * 128 + (((kc + fq) ^ (br & 7)) << 4);
                bfv[nf] = *reinterpret_cast<const bf16x8*>((const char*)Bs + byte);
            }
#pragma unroll
            for (int mf = 0; mf < 4; ++mf)
#pragma unroll
                for (int nf = 0; nf < 4; ++nf)
                    acc[mf][nf] = __builtin_amdgcn_mfma_f32_16x16x32_bf16(
                        af[mf], bfv[nf], acc[mf][nf], 0, 0, 0);
        }
    }

    // epilogue: C row = (l>>4)*4 + reg, col = l&15 (m89-verified layout)
#pragma unroll
    for (int mf = 0; mf < 4; ++mf) {
#pragma unroll
        for (int nf = 0; nf < 4; ++nf) {
            int n = n0 + wc * 64 + nf * 16 + fr;
            if (n < Nmax) {
#pragma unroll
                for (int j = 0; j < 4; ++j) {
                    int m = m0 + wr * 64 + mf * 16 + fq * 4 + j;
                    float v = acc[mf][nf][j];
                    if (bias)  v += bias[n];
                    if (res)   v += res[(size_t)m * ldC + n];
                    if (relu)  v = fmaxf(v, 0.f);
                    if (out32) out32[(size_t)m * ldC + n] = v;
                    if (out16) out16[(size_t)m * ld16 + n] = f2bf(v);
                }
            }
        }
    }
}

// ---------------------------------------------------------------------------
// Attention fp32: block per (qtile of 32 rows, head, batch), 256 threads.
// qkv fp32 [BT][1152] (q at h*64, k at 384+h*64, v at 768+h*64).
// LDS: S[32][260] + Q[32][64] = 41.3 KB -> 3 blocks/CU.
// Out: o bf16 [BT][384] (concat heads), feeds proj GEMM.
// ---------------------------------------------------------------------------
__global__ __launch_bounds__(256) void attn_k(const float* __restrict__ qkv,
                                              short* __restrict__ o) {
    __shared__ float S_lds[32][260];
    __shared__ float Qs[32][64];

    const int qt = blockIdx.x;            // 0..7
    const int hh = blockIdx.y;            // 0..5
    const int bb = blockIdx.z;            // 0..63
    const int t  = threadIdx.x;
    const int q0 = qt * 32;
    const int bt0 = bb * TT;

    // stage Q (coalesced)
    {
        const int e = t & 63, r0 = t >> 6;
#pragma unroll
        for (int p = 0; p < 8; ++p) {
            int r = r0 + 4 * p;
            Qs[r][e] = qkv[(size_t)(bt0 + q0 + r) * 1152 + hh * 64 + e];
        }
    }
    __syncthreads();

    // S = Q K^T * scale with causal mask. Thread owns column c = t.
    {
        const int c = t;
        const int active = (c <= q0 + 31);
        const int rstart = active ? max(0, c - q0) : 32;
        float Kreg[64];
        if (active) {
            const float4* kp = (const float4*)(qkv + (size_t)(bt0 + c) * 1152 + 384 + hh * 64);
#pragma unroll
            for (int i = 0; i < 16; ++i) {
                float4 kv = kp[i];
                Kreg[i * 4 + 0] = kv.x; Kreg[i * 4 + 1] = kv.y;
                Kreg[i * 4 + 2] = kv.z; Kreg[i * 4 + 3] = kv.w;
            }
        }
        for (int r = 0; r < 32; ++r) {
            float sv = -1e30f;
            if (r >= rstart) {
                float acc = 0.f;
#pragma unroll
                for (int i = 0; i < 16; ++i) {
                    float4 qv = *(const float4*)&Qs[r][i * 4];
                    acc += qv.x * Kreg[i * 4 + 0] + qv.y * Kreg[i * 4 + 1]
                         + qv.z * Kreg[i * 4 + 2] + qv.w * Kreg[i * 4 + 3];
                }
                sv = acc * SCALE;
            }
            S_lds[r][c] = sv;
        }
    }
    __syncthreads();

    // softmax: wave w -> rows w*8..w*8+7, 8 lanes/row, stride-8 col mapping
    {
        const int lane = t & 63;
        const int r  = (t >> 6) * 8 + (lane >> 3);
        const int cg = lane & 7;
        float vals[32];
        float mx = -1e30f;
#pragma unroll
        for (int jj = 0; jj < 32; ++jj) {
            float sv = S_lds[r][cg + 8 * jj];
            vals[jj] = sv;
            mx = fmaxf(mx, sv);
        }
        mx = fmaxf(mx, __shfl_xor(mx, 1));
        mx = fmaxf(mx, __shfl_xor(mx, 2));
        mx = fmaxf(mx, __shfl_xor(mx, 4));
        float sum = 0.f;
#pragma unroll
        for (int jj = 0; jj < 32; ++jj) {
            float p = __expf(vals[jj] - mx);
            vals[jj] = p;
            sum += p;
        }
        sum += __shfl_xor(sum, 1);
        sum += __shfl_xor(sum, 2);
        sum += __shfl_xor(sum, 4);
        float inv = 1.0f / sum;
#pragma unroll
        for (int jj = 0; jj < 32; ++jj) S_lds[r][cg + 8 * jj] = vals[jj] * inv;
    }
    __syncthreads();

    // O = P @ V. Thread: row rr = t>>3, cols e0 = (t&7)*8.
    {
        const int rr = t >> 3;
        const int e0 = (t & 7) * 8;
        const int jmax = q0 + rr;
        float a0=0,a1=0,a2=0,a3=0,a4=0,a5=0,a6=0,a7=0;
        const float* vbase = qkv + 768 + hh * 64 + e0;
#pragma unroll 4
        for (int j = 0; j <= jmax; ++j) {
            float p = S_lds[rr][j];
            const float4* vp = (const float4*)(vbase + (size_t)(bt0 + j) * 1152);
            float4 v0 = vp[0], v1 = vp[1];
            a0 += p * v0.x; a1 += p * v0.y; a2 += p * v0.z; a3 += p * v0.w;
            a4 += p * v1.x; a5 += p * v1.y; a6 += p * v1.z; a7 += p * v1.w;
        }
        bf16x8 ov;
        ov[0]=f2bf(a0); ov[1]=f2bf(a1); ov[2]=f2bf(a2); ov[3]=f2bf(a3);
        ov[4]=f2bf(a4); ov[5]=f2bf(a5); ov[6]=f2bf(a6); ov[7]=f2bf(a7);
        *reinterpret_cast<bf16x8*>(o + (size_t)(bt0 + q0 + rr) * DD + hh * 64 + e0) = ov;
    }
}

// ---------------------------------------------------------------------------
// Host orchestration
// ---------------------------------------------------------------------------
extern "C" void kernel_launch(void* const* d_in, const int* in_sizes, int n_in,
                              void* d_out, int out_size, void* d_ws, size_t ws_size,
                              hipStream_t stream) {
    const int*   idx     = (const int*)d_in[0];
    const float* tok_emb = (const float*)d_in[1];
    const float* pos_emb = (const float*)d_in[2];
    const float* ln1_w   = (const float*)d_in[3];
    const float* ln1_b   = (const float*)d_in[4];
    const float* wq      = (const float*)d_in[5];
    const float* wk      = (const float*)d_in[6];
    const float* wv      = (const float*)d_in[7];
    const float* proj_w  = (const float*)d_in[8];
    const float* proj_b  = (const float*)d_in[9];
    const float* ln2_w   = (const float*)d_in[10];
    const float* ln2_b   = (const float*)d_in[11];
    const float* ff_w1   = (const float*)d_in[12];
    const float* ff_b1   = (const float*)d_in[13];
    const float* ff_w2   = (const float*)d_in[14];
    const float* ff_b2   = (const float*)d_in[15];
    const float* lnf_w   = (const float*)d_in[16];
    const float* lnf_b   = (const float*)d_in[17];
    const float* head_w  = (const float*)d_in[18];
    const float* head_b  = (const float*)d_in[19];
    float* out = (float*)d_out;

    // workspace carve-up (bytes)
    char* p = (char*)d_ws;
    float* x      = (float*)p;  p += (size_t)BT * DD * 4;        // 25.2 MB
    float* qkv    = (float*)p;  p += (size_t)BT * 1152 * 4;      // 75.5 MB
    short* h16    = (short*)p;  p += (size_t)BT * DD * 2;        // 12.6 MB
    short* o16    = (short*)p;  p += (size_t)BT * DD * 2;        // 12.6 MB
    short* ff16   = (short*)p;  p += (size_t)BT * FFD * 2;       // 50.3 MB
    short* wqkvT  = (short*)p;  p += (size_t)LL * 1152 * 384 * 2;
    short* projT  = (short*)p;  p += (size_t)LL * 384 * 384 * 2;
    short* ff1T   = (short*)p;  p += (size_t)LL * 1536 * 384 * 2;
    short* ff2T   = (short*)p;  p += (size_t)LL * 384 * 1536 * 2;
    short* headT  = (short*)p;  p += (size_t)128 * 384 * 2;

    const dim3 blk(256);

    // weight conversions (every call; graph-safe)
    qkvconv_k<<<dim3(2654208 / 256), blk, 0, stream>>>(wq, wk, wv, wqkvT);
    wconv_k<<<dim3(12, 12, 6), blk, 0, stream>>>(proj_w, projT, 384, 384, 384);
    wconv_k<<<dim3(48, 12, 6), blk, 0, stream>>>(ff_w1, ff1T, 384, 1536, 1536);
    wconv_k<<<dim3(12, 48, 6), blk, 0, stream>>>(ff_w2, ff2T, 1536, 384, 384);
    wconv_k<<<dim3(4, 12, 1), blk, 0, stream>>>(head_w, headT, 384, 65, 128);

    embed_k<<<dim3((BT * 96) / 256), blk, 0, stream>>>(idx, tok_emb, pos_emb, x);

    const dim3 gLN(BT / 4);
    const dim3 gAttn(8, HH, BB);
    const dim3 gQKV(1152 / 128, BT / 128);
    const dim3 gD(384 / 128, BT / 128);
    const dim3 gFF(1536 / 128, BT / 128);
    const dim3 gHead(1, BT / 128);

    for (int l = 0; l < LL; ++l) {
        const size_t dOff = (size_t)l * DD;

        ln_k<<<gLN, blk, 0, stream>>>(x, ln1_w + dOff, ln1_b + dOff, h16);

        // qkv = h @ Wqkv   (fp32 out [BT][1152])
        gemm_bf16_k<<<gQKV, blk, 0, stream>>>(h16, wqkvT + (size_t)l * 1152 * 384,
                                              nullptr, nullptr, qkv, nullptr,
                                              BT, 384, 1152, 0, 1152, 0);

        attn_k<<<gAttn, blk, 0, stream>>>(qkv, o16);

        // x = x + o @ proj_w + proj_b
        gemm_bf16_k<<<gD, blk, 0, stream>>>(o16, projT + (size_t)l * 384 * 384,
                                            proj_b + dOff, x, x, nullptr,
                                            BT, 384, 384, 0, 384, 0);

        ln_k<<<gLN, blk, 0, stream>>>(x, ln2_w + dOff, ln2_b + dOff, h16);

        // ff = relu(h @ W1 + b1)  (bf16 out)
        gemm_bf16_k<<<gFF, blk, 0, stream>>>(h16, ff1T + (size_t)l * 1536 * 384,
                                             ff_b1 + (size_t)l * FFD, nullptr,
                                             nullptr, ff16,
                                             BT, 384, 1536, 1536, 1536, 1);

        // x = x + ff @ W2 + b2
        gemm_bf16_k<<<gD, blk, 0, stream>>>(ff16, ff2T + (size_t)l * 384 * 1536,
                                            ff_b2 + dOff, x, x, nullptr,
                                            BT, 1536, 384, 0, 384, 0);
    }

    ln_k<<<gLN, blk, 0, stream>>>(x, lnf_w, lnf_b, h16);
    // logits = h @ head_w + head_b   (N padded to 128, store guard 65)
    gemm_bf16_k<<<gHead, blk, 0, stream>>>(h16, headT, head_b, nullptr, out, nullptr,
                                           BT, 384, 65, 0, 65, 0);
}

// Round 3
// 1856.516 us; speedup vs baseline: 5.2656x; 1.6050x over previous
//
#include <hip/hip_runtime.h>
#include <hip/hip_bf16.h>
#include <math.h>

// Problem constants
#define BB   64
#define TT   256
#define VV   65
#define DD   384
#define HH   6
#define HDD  64
#define LL   6
#define FFD  1536
#define BT   (BB * TT)        // 16384 rows
#define EPSL 1e-5f
#define SCALE 0.05103103630798287f  // 384^-0.5

using bf16x8 = __attribute__((ext_vector_type(8))) short;
using f32x4  = __attribute__((ext_vector_type(4))) float;

__device__ __forceinline__ short f2bf(float f) {
    __hip_bfloat16 h = __float2bfloat16(f);
    return *reinterpret_cast<short*>(&h);
}

__device__ __forceinline__ void load_lds16(const void* g, void* lds_base) {
    __builtin_amdgcn_global_load_lds(
        (const __attribute__((address_space(1))) void*)g,
        (__attribute__((address_space(3))) void*)lds_base,
        16, 0, 0);
}

// ---------------------------------------------------------------------------
// Embedding
// ---------------------------------------------------------------------------
__global__ __launch_bounds__(256) void embed_k(const int* __restrict__ idx,
                                               const float* __restrict__ tok,
                                               const float* __restrict__ pos,
                                               float* __restrict__ x) {
    int i = blockIdx.x * 256 + threadIdx.x;
    int bt = i / 96;
    int d4 = i - bt * 96;
    int t  = bt & (TT - 1);
    float4 a = ((const float4*)tok)[(size_t)idx[bt] * 96 + d4];
    float4 p = ((const float4*)pos)[(size_t)t * 96 + d4];
    float4 o;
    o.x = a.x + p.x; o.y = a.y + p.y; o.z = a.z + p.z; o.w = a.w + p.w;
    ((float4*)x)[i] = o;
}

// ---------------------------------------------------------------------------
// LayerNorm fp32 in -> bf16 out
// ---------------------------------------------------------------------------
__global__ __launch_bounds__(256) void ln_k(const float* __restrict__ in,
                                            const float* __restrict__ w,
                                            const float* __restrict__ b,
                                            short* __restrict__ out) {
    int row  = blockIdx.x * 4 + (threadIdx.x >> 6);
    int lane = threadIdx.x & 63;
    const float* p = in + (size_t)row * DD;
    float vals[6];
    float s = 0.f;
#pragma unroll
    for (int j = 0; j < 6; ++j) { vals[j] = p[lane + 64 * j]; s += vals[j]; }
#pragma unroll
    for (int off = 32; off; off >>= 1) s += __shfl_xor(s, off);
    float mean = s * (1.0f / DD);
    float s2 = 0.f;
#pragma unroll
    for (int j = 0; j < 6; ++j) { float d = vals[j] - mean; s2 += d * d; }
#pragma unroll
    for (int off = 32; off; off >>= 1) s2 += __shfl_xor(s2, off);
    float rstd = rsqrtf(s2 * (1.0f / DD) + EPSL);
    short* po = out + (size_t)row * DD;
#pragma unroll
    for (int j = 0; j < 6; ++j) {
        int c = lane + 64 * j;
        po[c] = f2bf((vals[j] - mean) * rstd * w[c] + b[c]);
    }
}

// ---------------------------------------------------------------------------
// Weight transpose+convert: W[K][N] f32 -> Wt[Npad][K] bf16
// ---------------------------------------------------------------------------
__global__ __launch_bounds__(256) void wconv_k(const float* __restrict__ W,
                                               short* __restrict__ Wt,
                                               int K, int N, int Npad) {
    __shared__ float tile[32][33];
    W  += (size_t)blockIdx.z * K * N;
    Wt += (size_t)blockIdx.z * Npad * K;
    const int t  = threadIdx.x;
    const int c  = t & 31;
    const int r8 = t >> 5;
    const int k0 = blockIdx.y * 32;
    const int n0 = blockIdx.x * 32;
#pragma unroll
    for (int p = 0; p < 4; ++p) {
        int kk = r8 + 8 * p;
        int n  = n0 + c;
        tile[kk][c] = (n < N) ? W[(size_t)(k0 + kk) * N + n] : 0.f;
    }
    __syncthreads();
#pragma unroll
    for (int p = 0; p < 4; ++p) {
        int nl = r8 + 8 * p;
        Wt[(size_t)(n0 + nl) * K + k0 + c] = f2bf(tile[c][nl]);
    }
}

// ---------------------------------------------------------------------------
// QKV weight convert -> WqkvT [L][1152][384] bf16
// ---------------------------------------------------------------------------
__global__ __launch_bounds__(256) void qkvconv_k(const float* __restrict__ wq,
                                                 const float* __restrict__ wk,
                                                 const float* __restrict__ wv,
                                                 short* __restrict__ Wt) {
    int tid = blockIdx.x * 256 + threadIdx.x;
    int e  = tid & 63;
    int k  = (tid >> 6) % 384;
    int r2 = (tid >> 6) / 384;
    int h  = r2 % 6;
    int r3 = r2 / 6;
    int part = r3 % 3;
    int l  = r3 / 3;
    const float* src = (part == 0) ? wq : (part == 1) ? wk : wv;
    float v = src[(((size_t)l * 6 + h) * 384 + k) * 64 + e];
    Wt[((size_t)l * 1152 + part * 384 + h * 64 + e) * 384 + k] = f2bf(v);
}

// ---------------------------------------------------------------------------
// bf16 MFMA GEMM: C[M,N] = A[M,K] @ Bt[N,K]^T  (+bias)(+res)(ReLU)
// ---------------------------------------------------------------------------
__global__ __launch_bounds__(256) void gemm_bf16_k(
    const short* __restrict__ A,
    const short* __restrict__ Bt,
    const float* __restrict__ bias,
    const float* __restrict__ res,
    float* __restrict__ out32,
    short* __restrict__ out16,
    int M, int K, int ldC, int ld16, int Nmax, int relu) {
    __shared__ short As[128 * 64];
    __shared__ short Bs[128 * 64];
    const int t  = threadIdx.x;
    const int w  = t >> 6;
    const int l  = t & 63;
    const int m0 = blockIdx.y * 128;
    const int n0 = blockIdx.x * 128;
    const int wr = w >> 1, wc = w & 1;
    const int fr = l & 15, fq = l >> 4;

    int srow[4], scol[4];
#pragma unroll
    for (int qi = 0; qi < 4; ++qi) {
        int S = (w * 4 + qi) * 1024 + l * 16;
        int r = S >> 7;
        int c = (S >> 4) & 7;
        srow[qi] = r;
        scol[qi] = c ^ (r & 7);
    }

    f32x4 acc[4][4];
#pragma unroll
    for (int i = 0; i < 4; ++i)
#pragma unroll
        for (int j = 0; j < 4; ++j) acc[i][j] = (f32x4)(0.0f);

    for (int k0 = 0; k0 < K; k0 += 64) {
        __syncthreads();
#pragma unroll
        for (int qi = 0; qi < 4; ++qi) {
            const short* ga = A + (size_t)(m0 + srow[qi]) * K + k0 + scol[qi] * 8;
            load_lds16(ga, (char*)As + (w * 4 + qi) * 1024);
        }
#pragma unroll
        for (int qi = 0; qi < 4; ++qi) {
            const short* gb = Bt + (size_t)(n0 + srow[qi]) * K + k0 + scol[qi] * 8;
            load_lds16(gb, (char*)Bs + (w * 4 + qi) * 1024);
        }
        asm volatile("s_waitcnt vmcnt(0)" ::: "memory");
        __syncthreads();

#pragma unroll
        for (int kk = 0; kk < 64; kk += 32) {
            bf16x8 af[4], bfv[4];
            const int kc = kk >> 3;
#pragma unroll
            for (int mf = 0; mf < 4; ++mf) {
                int ar = wr * 64 + mf * 16 + fr;
                int byte = ar * 128 + (((kc + fq) ^ (ar & 7)) << 4);
                af[mf] = *reinterpret_cast<const bf16x8*>((const char*)As + byte);
            }
#pragma unroll
            for (int nf = 0; nf < 4; ++nf) {
                int br = wc * 64 + nf * 16 + fr;
                int byte = br * 128 + (((kc + fq) ^ (br & 7)) << 4);
                bfv[nf] = *reinterpret_cast<const bf16x8*>((const char*)Bs + byte);
            }
#pragma unroll
            for (int mf = 0; mf < 4; ++mf)
#pragma unroll
                for (int nf = 0; nf < 4; ++nf)
                    acc[mf][nf] = __builtin_amdgcn_mfma_f32_16x16x32_bf16(
                        af[mf], bfv[nf], acc[mf][nf], 0, 0, 0);
        }
    }

#pragma unroll
    for (int mf = 0; mf < 4; ++mf) {
#pragma unroll
        for (int nf = 0; nf < 4; ++nf) {
            int n = n0 + wc * 64 + nf * 16 + fr;
            if (n < Nmax) {
#pragma unroll
                for (int j = 0; j < 4; ++j) {
                    int m = m0 + wr * 64 + mf * 16 + fq * 4 + j;
                    float v = acc[mf][nf][j];
                    if (bias)  v += bias[n];
                    if (res)   v += res[(size_t)m * ldC + n];
                    if (relu)  v = fmaxf(v, 0.f);
                    if (out32) out32[(size_t)m * ldC + n] = v;
                    if (out16) out16[(size_t)m * ld16 + n] = f2bf(v);
                }
            }
        }
    }
}

// ---------------------------------------------------------------------------
// MFMA flash attention. Block per (h, b), 4 waves; wave w owns q-rows
// [w*64, w*64+64). qkv bf16 [BT][1152]: q at h*64, k at 384+h*64, v at 768+h*64.
// Swapped QK^T: S^T = mfma(K, Q) -> column(-per-q) softmax is lane-local.
// P -> wave-private XOR-swizzled LDS -> A-frags for O = P @ V (V^T in LDS).
// LDS: Vt 32KB + 4x8KB P = 64KB.
// ---------------------------------------------------------------------------
__global__ __launch_bounds__(256) void attn_mfma_k(const short* __restrict__ qkv,
                                                   short* __restrict__ o) {
    __shared__ short Vt[16384];        // [64 d][256 k], byte = d*512 + k*2 ^ ((d&7)<<4)
    __shared__ short Pw[4][4096];      // per wave [64 q][64 k], byte = q*128 + k*2 ^ ((q&7)<<4)

    const int hh = blockIdx.x;
    const int bb = blockIdx.y;
    const int t  = threadIdx.x;
    const int w  = t >> 6;
    const int lane = t & 63;
    const int fr = lane & 15, fq = lane >> 4;
    const int bt0 = bb * TT;

    // ---- stage V^T (transposed, XOR-swizzled) ----
    {
        const int r0 = (t & 127) * 2;          // k-row pair
        const int dbase = (t >> 7) * 32;       // d-half
        const short* v0 = qkv + (size_t)(bt0 + r0) * 1152 + 768 + hh * 64 + dbase;
        short a0[32], a1[32];
#pragma unroll
        for (int i = 0; i < 4; ++i) {
            *(bf16x8*)(a0 + i * 8) = *(const bf16x8*)(v0 + i * 8);
            *(bf16x8*)(a1 + i * 8) = *(const bf16x8*)(v0 + 1152 + i * 8);
        }
#pragma unroll
        for (int i = 0; i < 32; ++i) {
            int d = dbase + i;
            int byte = (d * 512 + r0 * 2) ^ ((d & 7) << 4);
            unsigned int pk = (unsigned int)(unsigned short)a0[i] |
                              ((unsigned int)(unsigned short)a1[i] << 16);
            *(unsigned int*)((char*)Vt + byte) = pk;
        }
    }
    __syncthreads();

    char* PwW = (char*)Pw[w];

    // Q B-frags (fixed per wave): rows q = w*64 + nf*16 + fr, d contig
    bf16x8 qb[4][2];
#pragma unroll
    for (int nf = 0; nf < 4; ++nf)
#pragma unroll
        for (int ks = 0; ks < 2; ++ks)
            qb[nf][ks] = *(const bf16x8*)(qkv + (size_t)(bt0 + w * 64 + nf * 16 + fr) * 1152 +
                                          hh * 64 + ks * 32 + fq * 8);

    f32x4 o_acc[4][4];
#pragma unroll
    for (int i = 0; i < 4; ++i)
#pragma unroll
        for (int j = 0; j < 4; ++j) o_acc[i][j] = (f32x4)(0.0f);
    float m_run[4], l_run[4];
#pragma unroll
    for (int nf = 0; nf < 4; ++nf) { m_run[nf] = -1e30f; l_run[nf] = 0.f; }

    for (int kt = 0; kt <= w; ++kt) {
        // K A-frags: rows k = kt*64 + mf*16 + fr, d contig
        bf16x8 ak[4][2];
#pragma unroll
        for (int mf = 0; mf < 4; ++mf)
#pragma unroll
            for (int ks = 0; ks < 2; ++ks)
                ak[mf][ks] = *(const bf16x8*)(qkv + (size_t)(bt0 + kt * 64 + mf * 16 + fr) * 1152 +
                                              384 + hh * 64 + ks * 32 + fq * 8);

        // S^T = K @ Q^T : row = k (mf*16+fq*4+j), col = q (nf*16+fr)
        f32x4 s[4][4];
#pragma unroll
        for (int i = 0; i < 4; ++i)
#pragma unroll
            for (int j = 0; j < 4; ++j) s[i][j] = (f32x4)(0.0f);
#pragma unroll
        for (int ks = 0; ks < 2; ++ks)
#pragma unroll
            for (int mf = 0; mf < 4; ++mf)
#pragma unroll
                for (int nf = 0; nf < 4; ++nf)
                    s[mf][nf] = __builtin_amdgcn_mfma_f32_16x16x32_bf16(
                        ak[mf][ks], qb[nf][ks], s[mf][nf], 0, 0, 0);

        // scale + causal mask (diag tile only)
        const bool diag = (kt == w);
#pragma unroll
        for (int mf = 0; mf < 4; ++mf)
#pragma unroll
            for (int nf = 0; nf < 4; ++nf)
#pragma unroll
                for (int j = 0; j < 4; ++j) {
                    float v = s[mf][nf][j] * SCALE;
                    if (diag && (mf * 16 + fq * 4 + j > nf * 16 + fr)) v = -1e30f;
                    s[mf][nf][j] = v;
                }

        // per-q-column max (16 in-lane + 2 shfl)
        float fac[4];
#pragma unroll
        for (int nf = 0; nf < 4; ++nf) {
            float mx = -1e30f;
#pragma unroll
            for (int mf = 0; mf < 4; ++mf)
#pragma unroll
                for (int j = 0; j < 4; ++j) mx = fmaxf(mx, s[mf][nf][j]);
            mx = fmaxf(mx, __shfl_xor(mx, 16));
            mx = fmaxf(mx, __shfl_xor(mx, 32));
            float mnew = fmaxf(m_run[nf], mx);
            fac[nf] = __expf(m_run[nf] - mnew);
            m_run[nf] = mnew;
        }

        // P = exp(s - m), column sums
#pragma unroll
        for (int nf = 0; nf < 4; ++nf) {
            float ps = 0.f;
#pragma unroll
            for (int mf = 0; mf < 4; ++mf)
#pragma unroll
                for (int j = 0; j < 4; ++j) {
                    float p = __expf(s[mf][nf][j] - m_run[nf]);
                    s[mf][nf][j] = p;
                    ps += p;
                }
            ps += __shfl_xor(ps, 16);
            ps += __shfl_xor(ps, 32);
            l_run[nf] = l_run[nf] * fac[nf] + ps;
        }

        // write P (bf16) to wave-private LDS: q rows, k contig; b64 per (mf,nf)
#pragma unroll
        for (int mf = 0; mf < 4; ++mf)
#pragma unroll
            for (int nf = 0; nf < 4; ++nf) {
                unsigned long long pk =
                    (unsigned long long)(unsigned short)f2bf(s[mf][nf][0]) |
                    ((unsigned long long)(unsigned short)f2bf(s[mf][nf][1]) << 16) |
                    ((unsigned long long)(unsigned short)f2bf(s[mf][nf][2]) << 32) |
                    ((unsigned long long)(unsigned short)f2bf(s[mf][nf][3]) << 48);
                int q = nf * 16 + fr;
                int byte = (q * 128 + mf * 32 + fq * 8) ^ ((q & 7) << 4);
                *(unsigned long long*)(PwW + byte) = pk;
            }

        // rescale O by fac (broadcast per q-row)
#pragma unroll
        for (int j = 0; j < 4; ++j) {
            int src = (lane & 48) + ((lane & 48) >> 2) + j;
#pragma unroll
            for (int mo = 0; mo < 4; ++mo) {
                float f = __shfl(fac[mo], src);
#pragma unroll
                for (int df = 0; df < 4; ++df) o_acc[mo][df][j] *= f;
            }
        }

        // read P A-frags + Vt B-frags, accumulate O += P @ V
        bf16x8 ap[4][2], bv[4][2];
#pragma unroll
        for (int mo = 0; mo < 4; ++mo)
#pragma unroll
            for (int ks = 0; ks < 2; ++ks) {
                int byte = ((mo * 16 + fr) * 128 + ks * 64 + fq * 16) ^ ((fr & 7) << 4);
                ap[mo][ks] = *(const bf16x8*)(PwW + byte);
            }
#pragma unroll
        for (int df = 0; df < 4; ++df)
#pragma unroll
            for (int ks = 0; ks < 2; ++ks) {
                int byte = ((df * 16 + fr) * 512 + kt * 128 + ks * 64 + fq * 16) ^ ((fr & 7) << 4);
                bv[df][ks] = *(const bf16x8*)((const char*)Vt + byte);
            }
#pragma unroll
        for (int ks = 0; ks < 2; ++ks)
#pragma unroll
            for (int mo = 0; mo < 4; ++mo)
#pragma unroll
                for (int df = 0; df < 4; ++df)
                    o_acc[mo][df] = __builtin_amdgcn_mfma_f32_16x16x32_bf16(
                        ap[mo][ks], bv[df][ks], o_acc[mo][df], 0, 0, 0);
    }

    // epilogue: O /= l, write bf16 (concat heads)
    float linv[4];
#pragma unroll
    for (int nf = 0; nf < 4; ++nf) linv[nf] = 1.0f / l_run[nf];
#pragma unroll
    for (int j = 0; j < 4; ++j) {
        int src = (lane & 48) + ((lane & 48) >> 2) + j;
#pragma unroll
        for (int mo = 0; mo < 4; ++mo) {
            float li = __shfl(linv[mo], src);
#pragma unroll
            for (int df = 0; df < 4; ++df) {
                float val = o_acc[mo][df][j] * li;
                o[(size_t)(bt0 + w * 64 + mo * 16 + fq * 4 + j) * DD + hh * 64 + df * 16 + fr] =
                    f2bf(val);
            }
        }
    }
}

// ---------------------------------------------------------------------------
// Host orchestration
// ---------------------------------------------------------------------------
extern "C" void kernel_launch(void* const* d_in, const int* in_sizes, int n_in,
                              void* d_out, int out_size, void* d_ws, size_t ws_size,
                              hipStream_t stream) {
    const int*   idx     = (const int*)d_in[0];
    const float* tok_emb = (const float*)d_in[1];
    const float* pos_emb = (const float*)d_in[2];
    const float* ln1_w   = (const float*)d_in[3];
    const float* ln1_b   = (const float*)d_in[4];
    const float* wq      = (const float*)d_in[5];
    const float* wk      = (const float*)d_in[6];
    const float* wv      = (const float*)d_in[7];
    const float* proj_w  = (const float*)d_in[8];
    const float* proj_b  = (const float*)d_in[9];
    const float* ln2_w   = (const float*)d_in[10];
    const float* ln2_b   = (const float*)d_in[11];
    const float* ff_w1   = (const float*)d_in[12];
    const float* ff_b1   = (const float*)d_in[13];
    const float* ff_w2   = (const float*)d_in[14];
    const float* ff_b2   = (const float*)d_in[15];
    const float* lnf_w   = (const float*)d_in[16];
    const float* lnf_b   = (const float*)d_in[17];
    const float* head_w  = (const float*)d_in[18];
    const float* head_b  = (const float*)d_in[19];
    float* out = (float*)d_out;

    // workspace carve-up
    char* p = (char*)d_ws;
    float* x      = (float*)p;  p += (size_t)BT * DD * 4;        // 25.2 MB
    short* qkv16  = (short*)p;  p += (size_t)BT * 1152 * 2;      // 37.7 MB
    short* h16    = (short*)p;  p += (size_t)BT * DD * 2;        // 12.6 MB
    short* o16    = (short*)p;  p += (size_t)BT * DD * 2;        // 12.6 MB
    short* ff16   = (short*)p;  p += (size_t)BT * FFD * 2;       // 50.3 MB
    short* wqkvT  = (short*)p;  p += (size_t)LL * 1152 * 384 * 2;
    short* projT  = (short*)p;  p += (size_t)LL * 384 * 384 * 2;
    short* ff1T   = (short*)p;  p += (size_t)LL * 1536 * 384 * 2;
    short* ff2T   = (short*)p;  p += (size_t)LL * 384 * 1536 * 2;
    short* headT  = (short*)p;  p += (size_t)128 * 384 * 2;

    const dim3 blk(256);

    qkvconv_k<<<dim3(2654208 / 256), blk, 0, stream>>>(wq, wk, wv, wqkvT);
    wconv_k<<<dim3(12, 12, 6), blk, 0, stream>>>(proj_w, projT, 384, 384, 384);
    wconv_k<<<dim3(48, 12, 6), blk, 0, stream>>>(ff_w1, ff1T, 384, 1536, 1536);
    wconv_k<<<dim3(12, 48, 6), blk, 0, stream>>>(ff_w2, ff2T, 1536, 384, 384);
    wconv_k<<<dim3(4, 12, 1), blk, 0, stream>>>(head_w, headT, 384, 65, 128);

    embed_k<<<dim3((BT * 96) / 256), blk, 0, stream>>>(idx, tok_emb, pos_emb, x);

    const dim3 gLN(BT / 4);
    const dim3 gAttn(HH, BB);
    const dim3 gQKV(1152 / 128, BT / 128);
    const dim3 gD(384 / 128, BT / 128);
    const dim3 gFF(1536 / 128, BT / 128);
    const dim3 gHead(1, BT / 128);

    for (int l = 0; l < LL; ++l) {
        const size_t dOff = (size_t)l * DD;

        ln_k<<<gLN, blk, 0, stream>>>(x, ln1_w + dOff, ln1_b + dOff, h16);

        // qkv16 = h @ Wqkv (bf16 out)
        gemm_bf16_k<<<gQKV, blk, 0, stream>>>(h16, wqkvT + (size_t)l * 1152 * 384,
                                              nullptr, nullptr, nullptr, qkv16,
                                              BT, 384, 1152, 1152, 1152, 0);

        attn_mfma_k<<<gAttn, blk, 0, stream>>>(qkv16, o16);

        // x = x + o @ proj_w + proj_b
        gemm_bf16_k<<<gD, blk, 0, stream>>>(o16, projT + (size_t)l * 384 * 384,
                                            proj_b + dOff, x, x, nullptr,
                                            BT, 384, 384, 0, 384, 0);

        ln_k<<<gLN, blk, 0, stream>>>(x, ln2_w + dOff, ln2_b + dOff, h16);

        // ff = relu(h @ W1 + b1) (bf16 out)
        gemm_bf16_k<<<gFF, blk, 0, stream>>>(h16, ff1T + (size_t)l * 1536 * 384,
                                             ff_b1 + (size_t)l * FFD, nullptr,
                                             nullptr, ff16,
                                             BT, 384, 1536, 1536, 1536, 1);

        // x = x + ff @ W2 + b2
        gemm_bf16_k<<<gD, blk, 0, stream>>>(ff16, ff2T + (size_t)l * 384 * 1536,
                                            ff_b2 + dOff, x, x, nullptr,
                                            BT, 1536, 384, 0, 384, 0);
    }

    ln_k<<<gLN, blk, 0, stream>>>(x, lnf_w, lnf_b, h16);
    gemm_bf16_k<<<gHead, blk, 0, stream>>>(h16, headT, head_b, nullptr, out, nullptr,
                                           BT, 384, 65, 0, 65, 0);
}

// Round 4
// 1367.567 us; speedup vs baseline: 7.1483x; 1.3575x over previous
//
#include <hip/hip_runtime.h>
#include <hip/hip_bf16.h>
#include <math.h>

// Problem constants
#define BB   64
#define TT   256
#define VV   65
#define DD   384
#define HH   6
#define HDD  64
#define LL   6
#define FFD  1536
#define BT   (BB * TT)        // 16384 rows
#define EPSL 1e-5f
#define SCALE 0.05103103630798287f  // 384^-0.5

using bf16x8 = __attribute__((ext_vector_type(8))) short;
using f32x4  = __attribute__((ext_vector_type(4))) float;

__device__ __forceinline__ short f2bf(float f) {
    __hip_bfloat16 h = __float2bfloat16(f);
    return *reinterpret_cast<short*>(&h);
}

__device__ __forceinline__ void load_lds16(const void* g, void* lds_base) {
    __builtin_amdgcn_global_load_lds(
        (const __attribute__((address_space(1))) void*)g,
        (__attribute__((address_space(3))) void*)lds_base,
        16, 0, 0);
}

// ---------------------------------------------------------------------------
// Embedding
// ---------------------------------------------------------------------------
__global__ __launch_bounds__(256) void embed_k(const int* __restrict__ idx,
                                               const float* __restrict__ tok,
                                               const float* __restrict__ pos,
                                               float* __restrict__ x) {
    int i = blockIdx.x * 256 + threadIdx.x;
    int bt = i / 96;
    int d4 = i - bt * 96;
    int t  = bt & (TT - 1);
    float4 a = ((const float4*)tok)[(size_t)idx[bt] * 96 + d4];
    float4 p = ((const float4*)pos)[(size_t)t * 96 + d4];
    float4 o;
    o.x = a.x + p.x; o.y = a.y + p.y; o.z = a.z + p.z; o.w = a.w + p.w;
    ((float4*)x)[i] = o;
}

// ---------------------------------------------------------------------------
// LayerNorm fp32 in -> bf16 out
// ---------------------------------------------------------------------------
__global__ __launch_bounds__(256) void ln_k(const float* __restrict__ in,
                                            const float* __restrict__ w,
                                            const float* __restrict__ b,
                                            short* __restrict__ out) {
    int row  = blockIdx.x * 4 + (threadIdx.x >> 6);
    int lane = threadIdx.x & 63;
    const float* p = in + (size_t)row * DD;
    float vals[6];
    float s = 0.f;
#pragma unroll
    for (int j = 0; j < 6; ++j) { vals[j] = p[lane + 64 * j]; s += vals[j]; }
#pragma unroll
    for (int off = 32; off; off >>= 1) s += __shfl_xor(s, off);
    float mean = s * (1.0f / DD);
    float s2 = 0.f;
#pragma unroll
    for (int j = 0; j < 6; ++j) { float d = vals[j] - mean; s2 += d * d; }
#pragma unroll
    for (int off = 32; off; off >>= 1) s2 += __shfl_xor(s2, off);
    float rstd = rsqrtf(s2 * (1.0f / DD) + EPSL);
    short* po = out + (size_t)row * DD;
#pragma unroll
    for (int j = 0; j < 6; ++j) {
        int c = lane + 64 * j;
        po[c] = f2bf((vals[j] - mean) * rstd * w[c] + b[c]);
    }
}

// ---------------------------------------------------------------------------
// Weight transpose+convert: W[K][N] f32 -> Wt[Npad][K] bf16
// ---------------------------------------------------------------------------
__global__ __launch_bounds__(256) void wconv_k(const float* __restrict__ W,
                                               short* __restrict__ Wt,
                                               int K, int N, int Npad) {
    __shared__ float tile[32][33];
    W  += (size_t)blockIdx.z * K * N;
    Wt += (size_t)blockIdx.z * Npad * K;
    const int t  = threadIdx.x;
    const int c  = t & 31;
    const int r8 = t >> 5;
    const int k0 = blockIdx.y * 32;
    const int n0 = blockIdx.x * 32;
#pragma unroll
    for (int p = 0; p < 4; ++p) {
        int kk = r8 + 8 * p;
        int n  = n0 + c;
        tile[kk][c] = (n < N) ? W[(size_t)(k0 + kk) * N + n] : 0.f;
    }
    __syncthreads();
#pragma unroll
    for (int p = 0; p < 4; ++p) {
        int nl = r8 + 8 * p;
        Wt[(size_t)(n0 + nl) * K + k0 + c] = f2bf(tile[c][nl]);
    }
}

// ---------------------------------------------------------------------------
// QKV weight convert -> WqkvT [L][1152][384] bf16
// ---------------------------------------------------------------------------
__global__ __launch_bounds__(256) void qkvconv_k(const float* __restrict__ wq,
                                                 const float* __restrict__ wk,
                                                 const float* __restrict__ wv,
                                                 short* __restrict__ Wt) {
    int tid = blockIdx.x * 256 + threadIdx.x;
    int e  = tid & 63;
    int k  = (tid >> 6) % 384;
    int r2 = (tid >> 6) / 384;
    int h  = r2 % 6;
    int r3 = r2 / 6;
    int part = r3 % 3;
    int l  = r3 / 3;
    const float* src = (part == 0) ? wq : (part == 1) ? wk : wv;
    float v = src[(((size_t)l * 6 + h) * 384 + k) * 64 + e];
    Wt[((size_t)l * 1152 + part * 384 + h * 64 + e) * 384 + k] = f2bf(v);
}

// ---------------------------------------------------------------------------
// bf16 MFMA GEMM, 8 waves (512 thr), tile 128x128, BK=64, double-buffered
// 2-phase pipeline: STAGE(next) -> compute(cur) -> vmcnt(0)+barrier.
// C = A[M,K] @ Bt[N,K]^T (+bias)(+res)(ReLU); XCD chunk swizzle (nwg%8==0).
// Wave (wr=w>>2, wc=w&3) owns 64x32; frags mf 0..3, nf 0..1.
// ---------------------------------------------------------------------------
__global__ __launch_bounds__(512, 4) void gemm8_k(
    const short* __restrict__ A,
    const short* __restrict__ Bt,
    const float* __restrict__ bias,
    const float* __restrict__ res,
    float* __restrict__ out32,
    short* __restrict__ out16,
    int M, int K, int ldC, int ld16, int Nmax, int relu) {
    __shared__ short As[2][8192];
    __shared__ short Bs[2][8192];
    const int t  = threadIdx.x;
    const int w  = t >> 6;
    const int l  = t & 63;

    // XCD-aware chunk swizzle (all grids have nwg % 8 == 0)
    const int gx  = gridDim.x;
    const int nwg = gx * gridDim.y;
    const int lin = blockIdx.y * gx + blockIdx.x;
    const int cpx = nwg >> 3;
    const int swz = (lin & 7) * cpx + (lin >> 3);
    const int m0 = (swz / gx) * 128;
    const int n0 = (swz % gx) * 128;

    const int wr = w >> 2, wc = w & 3;
    const int fr = l & 15, fq = l >> 4;

    // staging geometry: slot = w*2+qi (16 slots x 1KB per 16KB tile)
    int srow[2], scol[2];
#pragma unroll
    for (int qi = 0; qi < 2; ++qi) {
        int S = (w * 2 + qi) * 1024 + l * 16;
        int r = S >> 7;
        int c = (S >> 4) & 7;
        srow[qi] = r;
        scol[qi] = c ^ (r & 7);
    }

    f32x4 acc[4][2];
#pragma unroll
    for (int i = 0; i < 4; ++i)
#pragma unroll
        for (int j = 0; j < 2; ++j) acc[i][j] = (f32x4)(0.0f);

    const int nt = K >> 6;
    int cur = 0;

    // prologue: stage tile 0
#pragma unroll
    for (int qi = 0; qi < 2; ++qi) {
        load_lds16(A + (size_t)(m0 + srow[qi]) * K + scol[qi] * 8,
                   (char*)As[0] + (w * 2 + qi) * 1024);
        load_lds16(Bt + (size_t)(n0 + srow[qi]) * K + scol[qi] * 8,
                   (char*)Bs[0] + (w * 2 + qi) * 1024);
    }
    asm volatile("s_waitcnt vmcnt(0)" ::: "memory");
    __syncthreads();

    for (int tk = 0; tk < nt; ++tk) {
        const int k1 = (tk + 1) << 6;
        if (tk + 1 < nt) {
#pragma unroll
            for (int qi = 0; qi < 2; ++qi) {
                load_lds16(A + (size_t)(m0 + srow[qi]) * K + k1 + scol[qi] * 8,
                           (char*)As[cur ^ 1] + (w * 2 + qi) * 1024);
                load_lds16(Bt + (size_t)(n0 + srow[qi]) * K + k1 + scol[qi] * 8,
                           (char*)Bs[cur ^ 1] + (w * 2 + qi) * 1024);
            }
        }
        // compute current tile
        const char* Ab = (const char*)As[cur];
        const char* Bb = (const char*)Bs[cur];
#pragma unroll
        for (int ks = 0; ks < 2; ++ks) {
            const int kc = ks * 4 + fq;
            bf16x8 af[4], bfv[2];
#pragma unroll
            for (int mf = 0; mf < 4; ++mf) {
                int ar = wr * 64 + mf * 16 + fr;
                af[mf] = *reinterpret_cast<const bf16x8*>(
                    Ab + ar * 128 + ((kc ^ (ar & 7)) << 4));
            }
#pragma unroll
            for (int nf = 0; nf < 2; ++nf) {
                int br = wc * 32 + nf * 16 + fr;
                bfv[nf] = *reinterpret_cast<const bf16x8*>(
                    Bb + br * 128 + ((kc ^ (br & 7)) << 4));
            }
#pragma unroll
            for (int mf = 0; mf < 4; ++mf)
#pragma unroll
                for (int nf = 0; nf < 2; ++nf)
                    acc[mf][nf] = __builtin_amdgcn_mfma_f32_16x16x32_bf16(
                        af[mf], bfv[nf], acc[mf][nf], 0, 0, 0);
        }
        if (tk + 1 < nt) {
            asm volatile("s_waitcnt vmcnt(0)" ::: "memory");
            __syncthreads();
            cur ^= 1;
        }
    }

    // epilogue
#pragma unroll
    for (int mf = 0; mf < 4; ++mf) {
#pragma unroll
        for (int nf = 0; nf < 2; ++nf) {
            int n = n0 + wc * 32 + nf * 16 + fr;
            if (n < Nmax) {
#pragma unroll
                for (int j = 0; j < 4; ++j) {
                    int m = m0 + wr * 64 + mf * 16 + fq * 4 + j;
                    float v = acc[mf][nf][j];
                    if (bias)  v += bias[n];
                    if (res)   v += res[(size_t)m * ldC + n];
                    if (relu)  v = fmaxf(v, 0.f);
                    if (out32) out32[(size_t)m * ldC + n] = v;
                    if (out16) out16[(size_t)m * ld16 + n] = f2bf(v);
                }
            }
        }
    }
}

// ---------------------------------------------------------------------------
// MFMA flash attention. Block per (h, b), 4 waves; wave w owns q-rows
// [w*64, w*64+64). qkv bf16 [BT][1152]: q at h*64, k at 384+h*64, v at 768+h*64.
// ---------------------------------------------------------------------------
__global__ __launch_bounds__(256) void attn_mfma_k(const short* __restrict__ qkv,
                                                   short* __restrict__ o) {
    __shared__ short Vt[16384];        // [64 d][256 k], byte = d*512 + k*2 ^ ((d&7)<<4)
    __shared__ short Pw[4][4096];      // per wave [64 q][64 k], byte = q*128 + k*2 ^ ((q&7)<<4)

    const int hh = blockIdx.x;
    const int bb = blockIdx.y;
    const int t  = threadIdx.x;
    const int w  = t >> 6;
    const int lane = t & 63;
    const int fr = lane & 15, fq = lane >> 4;
    const int bt0 = bb * TT;

    // ---- stage V^T (transposed, XOR-swizzled) ----
    {
        const int r0 = (t & 127) * 2;          // k-row pair
        const int dbase = (t >> 7) * 32;       // d-half
        const short* v0 = qkv + (size_t)(bt0 + r0) * 1152 + 768 + hh * 64 + dbase;
        short a0[32], a1[32];
#pragma unroll
        for (int i = 0; i < 4; ++i) {
            *(bf16x8*)(a0 + i * 8) = *(const bf16x8*)(v0 + i * 8);
            *(bf16x8*)(a1 + i * 8) = *(const bf16x8*)(v0 + 1152 + i * 8);
        }
#pragma unroll
        for (int i = 0; i < 32; ++i) {
            int d = dbase + i;
            int byte = (d * 512 + r0 * 2) ^ ((d & 7) << 4);
            unsigned int pk = (unsigned int)(unsigned short)a0[i] |
                              ((unsigned int)(unsigned short)a1[i] << 16);
            *(unsigned int*)((char*)Vt + byte) = pk;
        }
    }
    __syncthreads();

    char* PwW = (char*)Pw[w];

    bf16x8 qb[4][2];
#pragma unroll
    for (int nf = 0; nf < 4; ++nf)
#pragma unroll
        for (int ks = 0; ks < 2; ++ks)
            qb[nf][ks] = *(const bf16x8*)(qkv + (size_t)(bt0 + w * 64 + nf * 16 + fr) * 1152 +
                                          hh * 64 + ks * 32 + fq * 8);

    f32x4 o_acc[4][4];
#pragma unroll
    for (int i = 0; i < 4; ++i)
#pragma unroll
        for (int j = 0; j < 4; ++j) o_acc[i][j] = (f32x4)(0.0f);
    float m_run[4], l_run[4];
#pragma unroll
    for (int nf = 0; nf < 4; ++nf) { m_run[nf] = -1e30f; l_run[nf] = 0.f; }

    for (int kt = 0; kt <= w; ++kt) {
        bf16x8 ak[4][2];
#pragma unroll
        for (int mf = 0; mf < 4; ++mf)
#pragma unroll
            for (int ks = 0; ks < 2; ++ks)
                ak[mf][ks] = *(const bf16x8*)(qkv + (size_t)(bt0 + kt * 64 + mf * 16 + fr) * 1152 +
                                              384 + hh * 64 + ks * 32 + fq * 8);

        f32x4 s[4][4];
#pragma unroll
        for (int i = 0; i < 4; ++i)
#pragma unroll
            for (int j = 0; j < 4; ++j) s[i][j] = (f32x4)(0.0f);
#pragma unroll
        for (int ks = 0; ks < 2; ++ks)
#pragma unroll
            for (int mf = 0; mf < 4; ++mf)
#pragma unroll
                for (int nf = 0; nf < 4; ++nf)
                    s[mf][nf] = __builtin_amdgcn_mfma_f32_16x16x32_bf16(
                        ak[mf][ks], qb[nf][ks], s[mf][nf], 0, 0, 0);

        const bool diag = (kt == w);
#pragma unroll
        for (int mf = 0; mf < 4; ++mf)
#pragma unroll
            for (int nf = 0; nf < 4; ++nf)
#pragma unroll
                for (int j = 0; j < 4; ++j) {
                    float v = s[mf][nf][j] * SCALE;
                    if (diag && (mf * 16 + fq * 4 + j > nf * 16 + fr)) v = -1e30f;
                    s[mf][nf][j] = v;
                }

        float fac[4];
#pragma unroll
        for (int nf = 0; nf < 4; ++nf) {
            float mx = -1e30f;
#pragma unroll
            for (int mf = 0; mf < 4; ++mf)
#pragma unroll
                for (int j = 0; j < 4; ++j) mx = fmaxf(mx, s[mf][nf][j]);
            mx = fmaxf(mx, __shfl_xor(mx, 16));
            mx = fmaxf(mx, __shfl_xor(mx, 32));
            float mnew = fmaxf(m_run[nf], mx);
            fac[nf] = __expf(m_run[nf] - mnew);
            m_run[nf] = mnew;
        }

#pragma unroll
        for (int nf = 0; nf < 4; ++nf) {
            float ps = 0.f;
#pragma unroll
            for (int mf = 0; mf < 4; ++mf)
#pragma unroll
                for (int j = 0; j < 4; ++j) {
                    float p = __expf(s[mf][nf][j] - m_run[nf]);
                    s[mf][nf][j] = p;
                    ps += p;
                }
            ps += __shfl_xor(ps, 16);
            ps += __shfl_xor(ps, 32);
            l_run[nf] = l_run[nf] * fac[nf] + ps;
        }

#pragma unroll
        for (int mf = 0; mf < 4; ++mf)
#pragma unroll
            for (int nf = 0; nf < 4; ++nf) {
                unsigned long long pk =
                    (unsigned long long)(unsigned short)f2bf(s[mf][nf][0]) |
                    ((unsigned long long)(unsigned short)f2bf(s[mf][nf][1]) << 16) |
                    ((unsigned long long)(unsigned short)f2bf(s[mf][nf][2]) << 32) |
                    ((unsigned long long)(unsigned short)f2bf(s[mf][nf][3]) << 48);
                int q = nf * 16 + fr;
                int byte = (q * 128 + mf * 32 + fq * 8) ^ ((q & 7) << 4);
                *(unsigned long long*)(PwW + byte) = pk;
            }

#pragma unroll
        for (int j = 0; j < 4; ++j) {
            int src = (lane & 48) + ((lane & 48) >> 2) + j;
#pragma unroll
            for (int mo = 0; mo < 4; ++mo) {
                float f = __shfl(fac[mo], src);
#pragma unroll
                for (int df = 0; df < 4; ++df) o_acc[mo][df][j] *= f;
            }
        }

        bf16x8 ap[4][2], bv[4][2];
#pragma unroll
        for (int mo = 0; mo < 4; ++mo)
#pragma unroll
            for (int ks = 0; ks < 2; ++ks) {
                int byte = ((mo * 16 + fr) * 128 + ks * 64 + fq * 16) ^ ((fr & 7) << 4);
                ap[mo][ks] = *(const bf16x8*)(PwW + byte);
            }
#pragma unroll
        for (int df = 0; df < 4; ++df)
#pragma unroll
            for (int ks = 0; ks < 2; ++ks) {
                int byte = ((df * 16 + fr) * 512 + kt * 128 + ks * 64 + fq * 16) ^ ((fr & 7) << 4);
                bv[df][ks] = *(const bf16x8*)((const char*)Vt + byte);
            }
#pragma unroll
        for (int ks = 0; ks < 2; ++ks)
#pragma unroll
            for (int mo = 0; mo < 4; ++mo)
#pragma unroll
                for (int df = 0; df < 4; ++df)
                    o_acc[mo][df] = __builtin_amdgcn_mfma_f32_16x16x32_bf16(
                        ap[mo][ks], bv[df][ks], o_acc[mo][df], 0, 0, 0);
    }

    float linv[4];
#pragma unroll
    for (int nf = 0; nf < 4; ++nf) linv[nf] = 1.0f / l_run[nf];
#pragma unroll
    for (int j = 0; j < 4; ++j) {
        int src = (lane & 48) + ((lane & 48) >> 2) + j;
#pragma unroll
        for (int mo = 0; mo < 4; ++mo) {
            float li = __shfl(linv[mo], src);
#pragma unroll
            for (int df = 0; df < 4; ++df) {
                float val = o_acc[mo][df][j] * li;
                o[(size_t)(bt0 + w * 64 + mo * 16 + fq * 4 + j) * DD + hh * 64 + df * 16 + fr] =
                    f2bf(val);
            }
        }
    }
}

// ---------------------------------------------------------------------------
// Host orchestration
// ---------------------------------------------------------------------------
extern "C" void kernel_launch(void* const* d_in, const int* in_sizes, int n_in,
                              void* d_out, int out_size, void* d_ws, size_t ws_size,
                              hipStream_t stream) {
    const int*   idx     = (const int*)d_in[0];
    const float* tok_emb = (const float*)d_in[1];
    const float* pos_emb = (const float*)d_in[2];
    const float* ln1_w   = (const float*)d_in[3];
    const float* ln1_b   = (const float*)d_in[4];
    const float* wq      = (const float*)d_in[5];
    const float* wk      = (const float*)d_in[6];
    const float* wv      = (const float*)d_in[7];
    const float* proj_w  = (const float*)d_in[8];
    const float* proj_b  = (const float*)d_in[9];
    const float* ln2_w   = (const float*)d_in[10];
    const float* ln2_b   = (const float*)d_in[11];
    const float* ff_w1   = (const float*)d_in[12];
    const float* ff_b1   = (const float*)d_in[13];
    const float* ff_w2   = (const float*)d_in[14];
    const float* ff_b2   = (const float*)d_in[15];
    const float* lnf_w   = (const float*)d_in[16];
    const float* lnf_b   = (const float*)d_in[17];
    const float* head_w  = (const float*)d_in[18];
    const float* head_b  = (const float*)d_in[19];
    float* out = (float*)d_out;

    // workspace carve-up
    char* p = (char*)d_ws;
    float* x      = (float*)p;  p += (size_t)BT * DD * 4;        // 25.2 MB
    short* qkv16  = (short*)p;  p += (size_t)BT * 1152 * 2;      // 37.7 MB
    short* h16    = (short*)p;  p += (size_t)BT * DD * 2;        // 12.6 MB
    short* o16    = (short*)p;  p += (size_t)BT * DD * 2;        // 12.6 MB
    short* ff16   = (short*)p;  p += (size_t)BT * FFD * 2;       // 50.3 MB
    short* wqkvT  = (short*)p;  p += (size_t)LL * 1152 * 384 * 2;
    short* projT  = (short*)p;  p += (size_t)LL * 384 * 384 * 2;
    short* ff1T   = (short*)p;  p += (size_t)LL * 1536 * 384 * 2;
    short* ff2T   = (short*)p;  p += (size_t)LL * 384 * 1536 * 2;
    short* headT  = (short*)p;  p += (size_t)128 * 384 * 2;

    const dim3 blk(256);
    const dim3 blk512(512);

    qkvconv_k<<<dim3(2654208 / 256), blk, 0, stream>>>(wq, wk, wv, wqkvT);
    wconv_k<<<dim3(12, 12, 6), blk, 0, stream>>>(proj_w, projT, 384, 384, 384);
    wconv_k<<<dim3(48, 12, 6), blk, 0, stream>>>(ff_w1, ff1T, 384, 1536, 1536);
    wconv_k<<<dim3(12, 48, 6), blk, 0, stream>>>(ff_w2, ff2T, 1536, 384, 384);
    wconv_k<<<dim3(4, 12, 1), blk, 0, stream>>>(head_w, headT, 384, 65, 128);

    embed_k<<<dim3((BT * 96) / 256), blk, 0, stream>>>(idx, tok_emb, pos_emb, x);

    const dim3 gLN(BT / 4);
    const dim3 gAttn(HH, BB);
    const dim3 gQKV(1152 / 128, BT / 128);   // 1152 blocks
    const dim3 gD(384 / 128, BT / 128);      // 384 blocks
    const dim3 gFF(1536 / 128, BT / 128);    // 1536 blocks
    const dim3 gHead(1, BT / 128);           // 128 blocks

    for (int l = 0; l < LL; ++l) {
        const size_t dOff = (size_t)l * DD;

        ln_k<<<gLN, blk, 0, stream>>>(x, ln1_w + dOff, ln1_b + dOff, h16);

        // qkv16 = h @ Wqkv (bf16 out)
        gemm8_k<<<gQKV, blk512, 0, stream>>>(h16, wqkvT + (size_t)l * 1152 * 384,
                                             nullptr, nullptr, nullptr, qkv16,
                                             BT, 384, 1152, 1152, 1152, 0);

        attn_mfma_k<<<gAttn, blk, 0, stream>>>(qkv16, o16);

        // x = x + o @ proj_w + proj_b
        gemm8_k<<<gD, blk512, 0, stream>>>(o16, projT + (size_t)l * 384 * 384,
                                           proj_b + dOff, x, x, nullptr,
                                           BT, 384, 384, 0, 384, 0);

        ln_k<<<gLN, blk, 0, stream>>>(x, ln2_w + dOff, ln2_b + dOff, h16);

        // ff = relu(h @ W1 + b1) (bf16 out)
        gemm8_k<<<gFF, blk512, 0, stream>>>(h16, ff1T + (size_t)l * 1536 * 384,
                                            ff_b1 + (size_t)l * FFD, nullptr,
                                            nullptr, ff16,
                                            BT, 384, 1536, 1536, 1536, 1);

        // x = x + ff @ W2 + b2
        gemm8_k<<<gD, blk512, 0, stream>>>(ff16, ff2T + (size_t)l * 384 * 1536,
                                           ff_b2 + dOff, x, x, nullptr,
                                           BT, 1536, 384, 0, 384, 0);
    }

    ln_k<<<gLN, blk, 0, stream>>>(x, lnf_w, lnf_b, h16);
    gemm8_k<<<gHead, blk512, 0, stream>>>(h16, headT, head_b, nullptr, out, nullptr,
                                          BT, 384, 65, 0, 65, 0);
}